// Round 12
// baseline (299.688 us; speedup 1.0000x reference)
//
#include <hip/hip_runtime.h>
#include <math.h>

#define LR 0.05f

typedef __attribute__((ext_vector_type(8))) short short8;
typedef __attribute__((ext_vector_type(4))) short short4v;
typedef __attribute__((ext_vector_type(4))) float f32x4;

#define MFMA16(a, b, c) __builtin_amdgcn_mfma_f32_16x16x32_bf16(a, b, c, 0, 0, 0)

__device__ __forceinline__ unsigned short f2bf(float v) {
  unsigned int u = __float_as_uint(v);
  u += 0x7fffu + ((u >> 16) & 1u);
  return (unsigned short)(u >> 16);
}

__device__ __forceinline__ void ce2(float& a, float& b, bool asc) {
  float lo = fminf(a, b), hi = fmaxf(a, b);
  a = asc ? lo : hi; b = asc ? hi : lo;
}

// ---------------- prep: build FRAGMENT-ORDERED bf16 weight copies ------------
__global__ __launch_bounds__(256) void prep_kernel(
    const float* __restrict__ W1a, const float* __restrict__ W1b,
    const float* __restrict__ W2a, const float* __restrict__ W2b,
    unsigned short* __restrict__ W2bfA, unsigned short* __restrict__ W2bfB,
    unsigned short* __restrict__ W2TbfA, unsigned short* __restrict__ W2TbfB,
    unsigned short* __restrict__ W1TbfA, unsigned short* __restrict__ W1TbfB,
    unsigned short* __restrict__ W1tailA, unsigned short* __restrict__ W1tailB)
{
  int i = blockIdx.x * 256 + threadIdx.x;
  if (i < 131072) {
    const float* W2 = (i >> 16) ? W2b : W2a;
    unsigned short* o = (i >> 16) ? W2bfB : W2bfA;
    int j = i & 65535;
    int tile = j >> 9, within = j & 511;
    int l16 = within >> 5, rem = within & 31;
    int ct = tile >> 3, k = tile & 7;
    o[j] = f2bf(W2[(ct * 16 + l16) * 256 + k * 32 + rem]);
  } else if (i < 262144) {
    int i2 = i - 131072;
    const float* W2 = (i2 >> 16) ? W2b : W2a;
    unsigned short* o = (i2 >> 16) ? W2TbfB : W2TbfA;
    int j = i2 & 65535;
    int tile = j >> 9, within = j & 511;
    int l16 = within >> 5, rem = within & 31;
    int ct = tile >> 3, k = tile & 7;
    o[j] = f2bf(W2[(k * 32 + rem) * 256 + ct * 16 + l16]);
  } else if (i < 278528) {
    int i2 = i - 262144;
    const float* W1 = (i2 >> 13) ? W1b : W1a;
    unsigned short* o = (i2 >> 13) ? W1TbfB : W1TbfA;
    int j = i2 & 8191;
    int ct = j >> 9, within = j & 511;
    int l16 = within >> 5, rem = within & 31;
    o[j] = (rem < 23) ? f2bf(W1[rem * 256 + ct * 16 + l16]) : (unsigned short)0;
  } else if (i < 286720) {
    int i2 = i - 278528;
    const float* W1 = (i2 >> 12) ? W1b : W1a;
    unsigned short* o = (i2 >> 12) ? W1tailB : W1tailA;
    int j = i2 & 4095;
    int k = j >> 9, within = j & 511;
    int l16 = within >> 5, rem = within & 31;
    o[j] = (l16 < 6) ? f2bf(W1[(17 + l16) * 256 + k * 32 + rem]) : (unsigned short)0;
  }
}

// ---------------- fused: 5 x (score + SVGD) + epilogue, 2 batches per block --
// R11 = R7 exact structure (232us best; no-spill per-phase transients <=32 reg)
// + ONLY the K-phase merged accumulators from R10 (HW-validated there):
//   cs_d = sum kv*(S_jd - 2g*a_jd) replaces ks_d,kx_d;
//   u    = sum kv*(df.S)           replaces t1sum/kxs (in-loop XSsh deleted).
// R10 post-mortem: its k-outer hoists spilled (FETCH 12->132MB) and cancelled
// the K-merge gain; this round separates the variables.
__global__ __launch_bounds__(512, 4) void fused_kernel(
    const float* __restrict__ obs, const float* __restrict__ a0,
    const float* __restrict__ b1a, const float* __restrict__ b2a,
    const float* __restrict__ W3a, const float* __restrict__ b3a,
    const float* __restrict__ b1b, const float* __restrict__ b2b,
    const float* __restrict__ W3b, const float* __restrict__ b3b,
    const unsigned short* __restrict__ W2bfA, const unsigned short* __restrict__ W2bfB,
    const unsigned short* __restrict__ W2TbfA, const unsigned short* __restrict__ W2TbfB,
    const unsigned short* __restrict__ W1TbfA, const unsigned short* __restrict__ W1TbfB,
    const unsigned short* __restrict__ W1tailA, const unsigned short* __restrict__ W1tailB,
    float* __restrict__ out)
{
  __shared__ __align__(16) unsigned short buf0[64][264];  // h1a -> dh2c; sort alias
  __shared__ __align__(16) unsigned short buf1[64][264];  // h1b -> dh1_m
  __shared__ __align__(16) unsigned short xsm[64][32];    // bf16 x
  __shared__ __align__(16) float upool[1024];             // qpart[2][8][64] | redS[128][6]
  __shared__ float acur[64][6];
  __shared__ float Svv[64][6];
  __shared__ float XSsh[64];                              // epilogue scratch only
  __shared__ float logps[64];
  __shared__ float asq[64];
  __shared__ int   selsh[64];
  __shared__ float medsh[2][2];

  float (*qpart)[8][64] = (float (*)[8][64])upool;
  float (*redS)[6] = (float (*)[6])upool;

  const int t = threadIdx.x;
  const int lane = t & 63, wv = t >> 6, quad = lane >> 4, l16 = lane & 15;
  const int b = blockIdx.x;
  const long abase = (long)b * 384;
  const int wfrag = l16 * 32 + quad * 8;
  const int bq = t >> 8;
  const int tq = t & 255;
  const int eb = tq * 2;

  float* sortA = (float*)&buf0[0][0] + bq * 1024;
  float* sortB = sortA + 512;

  // triangular index map for sort elements (step-invariant, packed)
  int packij = 0;
  {
    #pragma unroll
    for (int m = 0; m < 2; ++m) {
      int e = eb + m;
      int ii = 0, jj = 0;
      if (e < 496) {
        float sq = sqrtf(992.25f - 2.0f * (float)e);
        ii = (int)(31.5f - sq);
        if (e >= ((ii + 1) * (62 - ii)) / 2) ++ii;
        else if (e < (ii * (63 - ii)) / 2) --ii;
        jj = ii + 1 + (e - (ii * (63 - ii)) / 2);
      }
      packij |= (ii | (jj << 5)) << (m * 10);
    }
  }

  // ---- init ----
  if (t < 384) { int r = t / 6, d = t - r * 6; acur[r][d] = a0[abase + t]; }
  if (t < 64) {
    float s = 0.f;
    #pragma unroll
    for (int d = 0; d < 6; ++d) { float x0 = a0[abase + t * 6 + d]; s += x0 * x0; }
    asq[t] = s; logps[t] = 0.f;
  }
  for (int idx = t; idx < 64 * 32; idx += 512) {
    int r = idx >> 5, k = idx & 31;
    float v = 0.f;
    if (k < 17) v = obs[((long)b * 64 + r) * 17 + k];
    else if (k < 23) v = a0[abase + r * 6 + (k - 17)];
    xsm[r][k] = f2bf(v);
  }
  __syncthreads();

  #pragma unroll 1
  for (int s = 0; s < 5; ++s) {
    // ---- sort element values (regs) from acur (per-batch triangle) ----
    float sv0 = 0.f, sv1 = 0.f;
    {
      int i0 = (packij & 31) + bq * 32, j0 = ((packij >> 5) & 31) + bq * 32;
      int i1 = ((packij >> 10) & 31) + bq * 32, j1 = ((packij >> 15) & 31) + bq * 32;
      #pragma unroll
      for (int d = 0; d < 6; ++d) {
        float d0 = acur[i0][d] - acur[j0][d]; sv0 += d0 * d0;
        float d1 = acur[i1][d] - acur[j1][d]; sv1 += d1 * d1;
      }
    }

    // ================= h1 both nets (swapped: A=W1T, B=x) ===================
    unsigned int m1a_bits = 0, m1b_bits = 0, m2a_bits = 0, m2b_bits = 0;
    {
      short8 bx[4];
      #pragma unroll
      for (int rt = 0; rt < 4; ++rt)
        bx[rt] = *(const short8*)&xsm[rt * 16 + l16][quad * 8];
      #pragma unroll 1
      for (int net = 0; net < 2; ++net) {
        const unsigned short* W1T = net ? W1TbfB : W1TbfA;
        const float* b1 = net ? b1b : b1a;
        unsigned short (*hbuf)[264] = net ? buf1 : buf0;
        unsigned int m1 = 0;
        #pragma unroll
        for (int c = 0; c < 2; ++c) {
          int ct = wv * 2 + c;
          short8 aw = *(const short8*)&W1T[ct * 512 + wfrag];
          f32x4 b1v = *(const f32x4*)&b1[ct * 16 + quad * 4];
          #pragma unroll
          for (int rt = 0; rt < 4; ++rt) {
            f32x4 z = {0.f, 0.f, 0.f, 0.f};
            f32x4 h = MFMA16(aw, bx[rt], z);
            short4v hv;
            #pragma unroll
            for (int g = 0; g < 4; ++g) {
              float v = h[g] + b1v[g];
              if (v > 0.f) m1 |= 1u << ((rt * 2 + c) * 4 + g);
              hv[g] = (v > 0.f) ? (short)f2bf(v) : (short)0;
            }
            *(short4v*)&hbuf[rt * 16 + l16][ct * 16 + quad * 4] = hv;
          }
        }
        if (net) m1b_bits = m1; else m1a_bits = m1;
      }
    }
    __syncthreads();  // B1

    // ================= h2 both nets + qpart (R7 structure) ==================
    #pragma unroll 1
    for (int net = 0; net < 2; ++net) {
      const unsigned short* W2T = net ? W2TbfB : W2TbfA;
      const float* b2 = net ? b2b : b2a;
      const float* W3 = net ? W3b : W3a;
      unsigned short (*hbuf)[264] = net ? buf1 : buf0;

      float pq[4] = {0.f, 0.f, 0.f, 0.f};
      unsigned int m2 = 0;

      #pragma unroll 1
      for (int ci = 0; ci < 2; ++ci) {
        int ct = wv * 2 + ci;
        f32x4 acc[4];
        acc[0] = acc[1] = acc[2] = acc[3] = (f32x4){0.f, 0.f, 0.f, 0.f};
        #pragma unroll 1
        for (int k = 0; k < 8; ++k) {
          short8 aw = *(const short8*)&W2T[ct * 4096 + k * 512 + wfrag];
          #pragma unroll
          for (int rt = 0; rt < 4; ++rt) {
            short8 hf = *(const short8*)&hbuf[rt * 16 + l16][k * 32 + quad * 8];
            acc[rt] = MFMA16(aw, hf, acc[rt]);
          }
        }
        f32x4 b2v = *(const f32x4*)&b2[ct * 16 + quad * 4];
        f32x4 w3v = *(const f32x4*)&W3[ct * 16 + quad * 4];
        #pragma unroll
        for (int rt = 0; rt < 4; ++rt)
          #pragma unroll
          for (int g = 0; g < 4; ++g) {
            float v = acc[rt][g] + b2v[g];
            if (v > 0.f) {
              m2 |= 1u << ((rt * 2 + ci) * 4 + g);
              pq[rt] += v * w3v[g];
            }
          }
      }
      if (net) m2b_bits = m2; else m2a_bits = m2;
      #pragma unroll
      for (int rt = 0; rt < 4; ++rt) {
        pq[rt] += __shfl_xor(pq[rt], 16);
        pq[rt] += __shfl_xor(pq[rt], 32);
      }
      if (quad == 0) {
        #pragma unroll
        for (int rt = 0; rt < 4; ++rt)
          qpart[net][wv][rt * 16 + l16] = pq[rt];
      }
    }
    __syncthreads();  // B2

    // ---- sel (t<64) + intra-wave sort k=2..128 (barrier bubble filler) ----
    if (t < 64) {
      float qa = b3a[0], qb = b3b[0];
      #pragma unroll
      for (int w = 0; w < 8; ++w) { qa += qpart[0][w][t]; qb += qpart[1][w][t]; }
      selsh[t] = (qa <= qb) ? 0 : 1;
    }
    #pragma unroll
    for (int k = 2; k <= 128; k <<= 1) {
      #pragma unroll
      for (int j = k >> 1; j >= 2; j >>= 1) {
        int lm = j >> 1;
        bool km = (((eb & j) == 0) == ((eb & k) == 0));
        float p0 = __shfl_xor(sv0, lm);
        sv0 = km ? fminf(sv0, p0) : fmaxf(sv0, p0);
        float p1 = __shfl_xor(sv1, lm);
        sv1 = km ? fminf(sv1, p1) : fmaxf(sv1, p1);
      }
      ce2(sv0, sv1, ((eb & k) == 0));
    }
    __syncthreads();  // B3

    // ---- dh2c: packed b64 masked writes -> buf0 ----
    #pragma unroll
    for (int ci = 0; ci < 2; ++ci) {
      int ct = wv * 2 + ci;
      f32x4 w3a4 = *(const f32x4*)&W3a[ct * 16 + quad * 4];
      f32x4 w3b4 = *(const f32x4*)&W3b[ct * 16 + quad * 4];
      #pragma unroll
      for (int rt = 0; rt < 4; ++rt) {
        int part = rt * 16 + l16;
        int sl = selsh[part];
        unsigned int mb = sl ? m2b_bits : m2a_bits;
        short4v dv;
        #pragma unroll
        for (int g = 0; g < 4; ++g) {
          int bit = (rt * 2 + ci) * 4 + g;
          unsigned short w3bf = f2bf(sl ? w3b4[g] : w3a4[g]);
          dv[g] = ((mb >> bit) & 1) ? (short)w3bf : (short)0;
        }
        *(short4v*)&buf0[part][ct * 16 + quad * 4] = dv;
      }
    }
    __syncthreads();  // B4

    // ---- bwd: 4 passes (net x col), swapped; packed gated b64 -> buf1 ----
    #pragma unroll 1
    for (int pass = 0; pass < 4; ++pass) {
      int net = pass >> 1, c = pass & 1;
      int ct = wv * 2 + c;
      const unsigned short* W2f = net ? W2bfB : W2bfA;
      f32x4 acc[4];
      acc[0] = acc[1] = acc[2] = acc[3] = (f32x4){0.f, 0.f, 0.f, 0.f};
      #pragma unroll 1
      for (int k = 0; k < 8; ++k) {
        short8 aw = *(const short8*)&W2f[ct * 4096 + k * 512 + wfrag];
        #pragma unroll
        for (int rt = 0; rt < 4; ++rt) {
          short8 dd = *(const short8*)&buf0[rt * 16 + l16][k * 32 + quad * 8];
          acc[rt] = MFMA16(aw, dd, acc[rt]);
        }
      }
      unsigned int mb = net ? m1b_bits : m1a_bits;
      #pragma unroll
      for (int rt = 0; rt < 4; ++rt) {
        int part = rt * 16 + l16;
        if (selsh[part] == net) {
          short4v dv;
          #pragma unroll
          for (int g = 0; g < 4; ++g) {
            int bit = (rt * 2 + c) * 4 + g;
            dv[g] = ((mb >> bit) & 1) ? (short)f2bf(acc[rt][g]) : (short)0;
          }
          *(short4v*)&buf1[part][ct * 16 + quad * 4] = dv;
        }
      }
    }
    __syncthreads();  // B5

    // ---- S (wave: net = wv>>2, rt = wv&3; swapped) + sort stage1 write ----
    {
      int netS = wv >> 2, rt = wv & 3;
      const unsigned short* Wt = netS ? W1tailB : W1tailA;
      f32x4 sacc = {0.f, 0.f, 0.f, 0.f};
      #pragma unroll 1
      for (int k = 0; k < 8; ++k) {
        short8 a = *(const short8*)&buf1[rt * 16 + l16][k * 32 + quad * 8];
        short8 bb2 = *(const short8*)&Wt[k * 512 + wfrag];
        sacc = MFMA16(bb2, a, sacc);   // lane: 4 d-rows x 1 particle
      }
      #pragma unroll
      for (int g = 0; g < 4; ++g) {
        int d = quad * 4 + g;
        if (d < 6) redS[netS * 64 + rt * 16 + l16][d] = sacc[g];
      }
    }
    sortA[eb] = sv0; sortA[eb + 1] = sv1;
    __syncthreads();  // B6

    // ---- sort stage1 read (k=256, j=128) + tail + Svv fill + stage2 write --
    {
      bool km = (((eb & 128) == 0) == ((eb & 256) == 0));
      float p0 = sortA[eb ^ 128];
      float p1 = sortA[(eb ^ 128) + 1];
      sv0 = km ? fminf(sv0, p0) : fmaxf(sv0, p0);
      sv1 = km ? fminf(sv1, p1) : fmaxf(sv1, p1);
      #pragma unroll
      for (int j = 64; j >= 2; j >>= 1) {
        int lm = j >> 1;
        bool k2 = (((eb & j) == 0) == ((eb & 256) == 0));
        float q0 = __shfl_xor(sv0, lm);
        sv0 = k2 ? fminf(sv0, q0) : fmaxf(sv0, q0);
        float q1 = __shfl_xor(sv1, lm);
        sv1 = k2 ? fminf(sv1, q1) : fmaxf(sv1, q1);
      }
      ce2(sv0, sv1, ((eb & 256) == 0));
    }
    if (t < 384) { int r = t / 6, d = t - r * 6; Svv[r][d] = redS[selsh[r] * 64 + r][d]; }
    sortB[eb] = sv0; sortB[eb + 1] = sv1;
    __syncthreads();  // B7

    // ---- sort stage2 read (k=512, j=256) + stage3 write ----
    {
      bool km = ((eb & 256) == 0);
      float p0 = sortB[eb ^ 256];
      float p1 = sortB[(eb ^ 256) + 1];
      sv0 = km ? fminf(sv0, p0) : fmaxf(sv0, p0);
      sv1 = km ? fminf(sv1, p1) : fmaxf(sv1, p1);
    }
    sortA[eb] = sv0; sortA[eb + 1] = sv1;
    __syncthreads();  // B8

    // ---- sort stage3 read (j=128) + final tail + median ----
    {
      bool km = ((eb & 128) == 0);
      float p0 = sortA[eb ^ 128];
      float p1 = sortA[(eb ^ 128) + 1];
      sv0 = km ? fminf(sv0, p0) : fmaxf(sv0, p0);
      sv1 = km ? fminf(sv1, p1) : fmaxf(sv1, p1);
      #pragma unroll
      for (int j = 64; j >= 2; j >>= 1) {
        int lm = j >> 1;
        bool k2 = ((eb & j) == 0);
        float q0 = __shfl_xor(sv0, lm);
        sv0 = k2 ? fminf(sv0, q0) : fmaxf(sv0, q0);
        float q1 = __shfl_xor(sv1, lm);
        sv1 = k2 ? fminf(sv1, q1) : fmaxf(sv1, q1);
      }
      ce2(sv0, sv1, true);
    }
    if (tq == 127) medsh[bq][0] = sv1;  // element 255 of this batch
    if (tq == 128) medsh[bq][1] = sv0;  // element 256 of this batch
    __syncthreads();  // B9

    // ======== K row-sums + update (merged accumulators: 9 quantities) =======
    float med = 0.5f * (medsh[bq][0] + medsh[bq][1]);
    float g = 1.0f / (2.0f * (med / logf(33.0f)) + 1e-8f);
    float g2 = 2.0f * g;

    const int i = t >> 3, l = t & 7;   // i in [0,64); batch of row i = bq
    const int jb = i & 32;
    float ai0 = acur[i][0], ai1 = acur[i][1], ai2 = acur[i][2];
    float ai3 = acur[i][3], ai4 = acur[i][4], ai5 = acur[i][5];
    float cs0=0,cs1=0,cs2=0,cs3=0,cs4=0,cs5=0;
    float krow=0.f, kd2=0.f, u=0.f;
    #pragma unroll
    for (int jj = 0; jj < 4; ++jj) {
      int j = jb + l + 8 * jj;
      float aj0 = acur[j][0], aj1 = acur[j][1], aj2 = acur[j][2];
      float aj3 = acur[j][3], aj4 = acur[j][4], aj5 = acur[j][5];
      float S0 = Svv[j][0], S1 = Svv[j][1], S2 = Svv[j][2];
      float S3 = Svv[j][3], S4 = Svv[j][4], S5 = Svv[j][5];
      float df0 = ai0 - aj0, df1 = ai1 - aj1, df2 = ai2 - aj2;
      float df3 = ai3 - aj3, df4 = ai4 - aj4, df5 = ai5 - aj5;
      float dv = df0*df0 + df1*df1 + df2*df2 + df3*df3 + df4*df4 + df5*df5;
      float kv = expf(-g * dv);
      krow += kv; kd2 += kv * dv;
      float w = df0*S0 + df1*S1 + df2*S2 + df3*S3 + df4*S4 + df5*S5;
      u = fmaf(kv, w, u);
      cs0 = fmaf(kv, fmaf(-g2, aj0, S0), cs0);
      cs1 = fmaf(kv, fmaf(-g2, aj1, S1), cs1);
      cs2 = fmaf(kv, fmaf(-g2, aj2, S2), cs2);
      cs3 = fmaf(kv, fmaf(-g2, aj3, S3), cs3);
      cs4 = fmaf(kv, fmaf(-g2, aj4, S4), cs4);
      cs5 = fmaf(kv, fmaf(-g2, aj5, S5), cs5);
    }
    #pragma unroll
    for (int off = 4; off > 0; off >>= 1) {
      krow += __shfl_down(krow, off, 8);
      kd2  += __shfl_down(kd2,  off, 8);
      u    += __shfl_down(u,    off, 8);
      cs0 += __shfl_down(cs0, off, 8);
      cs1 += __shfl_down(cs1, off, 8);
      cs2 += __shfl_down(cs2, off, 8);
      cs3 += __shfl_down(cs3, off, 8);
      cs4 += __shfl_down(cs4, off, 8);
      cs5 += __shfl_down(cs5, off, 8);
    }
    float an0=0,an1=0,an2=0,an3=0,an4=0,an5=0, lpnew=0;
    if (l == 0) {
      const float inv_n = 1.0f / 32.0f;
      float gk = g2 * krow;
      an0 = ai0 + LR * ((cs0 + ai0 * gk) * inv_n);
      an1 = ai1 + LR * ((cs1 + ai1 * gk) * inv_n);
      an2 = ai2 + LR * ((cs2 + ai2 * gk) * inv_n);
      an3 = ai3 + LR * ((cs3 + ai3 * gk) * inv_n);
      an4 = ai4 + LR * ((cs4 + ai4 * gk) * inv_n);
      an5 = ai5 + LR * ((cs5 + ai5 * gk) * inv_n);
      float term1 = (-g2 / 31.f) * u;
      float term2 = (-g2 / 31.f) * (g2 * kd2 - 6.f * (krow - 1.f));
      lpnew = logps[i] - LR * (term1 + term2);
    }
    __syncthreads();  // B10
    if (l == 0) {
      acur[i][0] = an0; acur[i][1] = an1; acur[i][2] = an2;
      acur[i][3] = an3; acur[i][4] = an4; acur[i][5] = an5;
      logps[i] = lpnew;
      xsm[i][17] = f2bf(an0); xsm[i][18] = f2bf(an1); xsm[i][19] = f2bf(an2);
      xsm[i][20] = f2bf(an3); xsm[i][21] = f2bf(an4); xsm[i][22] = f2bf(an5);
    }
    __syncthreads();  // B11
  }

  // ================= epilogue =================
  if (t < 384) { int r = t / 6, d = t - r * 6; out[abase + t] = tanhf(acur[r][d]); }
  if (t < 64) {
    float st = 0.f;
    #pragma unroll
    for (int d = 0; d < 6; ++d) {
      float x = acur[t][d];
      float z = -2.f * x;
      float sp = fmaxf(z, 0.f) + log1pf(expf(-fabsf(z)));
      st += 2.f * (0.69314718056f - x - sp);
    }
    float lpn = -3.0f * logf(1.88495559215f) - (0.5f / 0.3f) * asq[t];
    XSsh[t] = lpn + logps[t] - st;
  }
  __syncthreads();
  if (tq == 0) {
    float s = 0.f;
    #pragma unroll
    for (int n = 0; n < 32; ++n) s += XSsh[bq * 32 + n];
    out[196608 + 2 * b + bq] = s * (1.0f / 32.0f);
  }
}

extern "C" void kernel_launch(void* const* d_in, const int* in_sizes, int n_in,
                              void* d_out, int out_size, void* d_ws, size_t ws_size,
                              hipStream_t stream) {
  const float* obs  = (const float*)d_in[0];
  const float* a0   = (const float*)d_in[1];
  const float* q1W1 = (const float*)d_in[2];
  const float* q1b1 = (const float*)d_in[3];
  const float* q1W2 = (const float*)d_in[4];
  const float* q1b2 = (const float*)d_in[5];
  const float* q1W3 = (const float*)d_in[6];
  const float* q1b3 = (const float*)d_in[7];
  const float* q2W1 = (const float*)d_in[8];
  const float* q2b1 = (const float*)d_in[9];
  const float* q2W2 = (const float*)d_in[10];
  const float* q2b2 = (const float*)d_in[11];
  const float* q2W3 = (const float*)d_in[12];
  const float* q2b3 = (const float*)d_in[13];

  unsigned short* wsu = (unsigned short*)d_ws;
  unsigned short* W2bfA  = wsu;
  unsigned short* W2bfB  = W2bfA + 65536;
  unsigned short* W2TbfA = W2bfB + 65536;
  unsigned short* W2TbfB = W2TbfA + 65536;
  unsigned short* W1TbfA = W2TbfB + 65536;
  unsigned short* W1TbfB = W1TbfA + 8192;
  unsigned short* W1tailA = W1TbfB + 8192;
  unsigned short* W1tailB = W1tailA + 4096;
  float* out  = (float*)d_out;

  prep_kernel<<<1120, 256, 0, stream>>>(q1W1, q2W1, q1W2, q2W2,
      W2bfA, W2bfB, W2TbfA, W2TbfB, W1TbfA, W1TbfB, W1tailA, W1tailB);

  fused_kernel<<<512, 512, 0, stream>>>(obs, a0,
      q1b1, q1b2, q1W3, q1b3,
      q2b1, q2b2, q2W3, q2b3,
      W2bfA, W2bfB, W2TbfA, W2TbfB, W1TbfA, W1TbfB, W1tailA, W1tailB,
      out);
}

// Round 13
// 253.861 us; speedup vs baseline: 1.1805x; 1.1805x over previous
//
#include <hip/hip_runtime.h>
#include <math.h>

#define LR 0.05f

typedef __attribute__((ext_vector_type(8))) short short8;
typedef __attribute__((ext_vector_type(4))) short short4v;
typedef __attribute__((ext_vector_type(4))) float f32x4;
typedef __attribute__((ext_vector_type(2))) unsigned int uint2v;

#define MFMA16(a, b, c) __builtin_amdgcn_mfma_f32_16x16x32_bf16(a, b, c, 0, 0, 0)

__device__ __forceinline__ unsigned short f2bf(float v) {
  unsigned int u = __float_as_uint(v);
  u += 0x7fffu + ((u >> 16) & 1u);
  return (unsigned short)(u >> 16);
}

// pack 2 floats -> 2 bf16 (RNE) in one HW instruction (gfx950)
__device__ __forceinline__ unsigned int pkbf(float a, float b) {
  unsigned int r;
  asm("v_cvt_pk_bf16_f32 %0, %1, %2" : "=v"(r) : "v"(a), "v"(b));
  return r;
}

__device__ __forceinline__ void ce2(float& a, float& b, bool asc) {
  float lo = fminf(a, b), hi = fmaxf(a, b);
  a = asc ? lo : hi; b = asc ? hi : lo;
}

// ---------------- prep: FRAGMENT-ORDERED bf16 weights + bf16 W3 table --------
__global__ __launch_bounds__(256) void prep_kernel(
    const float* __restrict__ W1a, const float* __restrict__ W1b,
    const float* __restrict__ W2a, const float* __restrict__ W2b,
    const float* __restrict__ W3a, const float* __restrict__ W3b,
    unsigned short* __restrict__ W2bfA, unsigned short* __restrict__ W2bfB,
    unsigned short* __restrict__ W2TbfA, unsigned short* __restrict__ W2TbfB,
    unsigned short* __restrict__ W1TbfA, unsigned short* __restrict__ W1TbfB,
    unsigned short* __restrict__ W1tailA, unsigned short* __restrict__ W1tailB,
    unsigned short* __restrict__ W3bfA, unsigned short* __restrict__ W3bfB)
{
  int i = blockIdx.x * 256 + threadIdx.x;
  if (i < 131072) {
    const float* W2 = (i >> 16) ? W2b : W2a;
    unsigned short* o = (i >> 16) ? W2bfB : W2bfA;
    int j = i & 65535;
    int tile = j >> 9, within = j & 511;
    int l16 = within >> 5, rem = within & 31;
    int ct = tile >> 3, k = tile & 7;
    o[j] = f2bf(W2[(ct * 16 + l16) * 256 + k * 32 + rem]);
  } else if (i < 262144) {
    int i2 = i - 131072;
    const float* W2 = (i2 >> 16) ? W2b : W2a;
    unsigned short* o = (i2 >> 16) ? W2TbfB : W2TbfA;
    int j = i2 & 65535;
    int tile = j >> 9, within = j & 511;
    int l16 = within >> 5, rem = within & 31;
    int ct = tile >> 3, k = tile & 7;
    o[j] = f2bf(W2[(k * 32 + rem) * 256 + ct * 16 + l16]);
  } else if (i < 278528) {
    int i2 = i - 262144;
    const float* W1 = (i2 >> 13) ? W1b : W1a;
    unsigned short* o = (i2 >> 13) ? W1TbfB : W1TbfA;
    int j = i2 & 8191;
    int ct = j >> 9, within = j & 511;
    int l16 = within >> 5, rem = within & 31;
    o[j] = (rem < 23) ? f2bf(W1[rem * 256 + ct * 16 + l16]) : (unsigned short)0;
  } else if (i < 286720) {
    int i2 = i - 278528;
    const float* W1 = (i2 >> 12) ? W1b : W1a;
    unsigned short* o = (i2 >> 12) ? W1tailB : W1tailA;
    int j = i2 & 4095;
    int k = j >> 9, within = j & 511;
    int l16 = within >> 5, rem = within & 31;
    o[j] = (l16 < 6) ? f2bf(W1[(17 + l16) * 256 + k * 32 + rem]) : (unsigned short)0;
  } else if (i < 287232) {
    int i2 = i - 286720;
    int net = i2 >> 8, col = i2 & 255;
    const float* W3 = net ? W3b : W3a;
    unsigned short* o = net ? W3bfB : W3bfA;
    o[col] = f2bf(W3[col]);
  }
}

// ---------------- fused: 5 x (score + SVGD) + epilogue, 2 batches per block --
// R12 = R7 exact structure (232us verified best; R10 k-outer spilled, R11
// K-merge regressed -- both reverted) + f2bf elimination:
//  - dh2c: bf16(W3) precomputed in prep (step-invariant; was 32 f2bf/step)
//  - h1/bwd: v_cvt_pk_bf16_f32 pairs (RNE, = f2bf bit-identical; gate float
//    to 0 before pack, bf16(0)=0x0000 matches old masked path)
__global__ __launch_bounds__(512, 4) void fused_kernel(
    const float* __restrict__ obs, const float* __restrict__ a0,
    const float* __restrict__ b1a, const float* __restrict__ b2a,
    const float* __restrict__ W3a, const float* __restrict__ b3a,
    const float* __restrict__ b1b, const float* __restrict__ b2b,
    const float* __restrict__ W3b, const float* __restrict__ b3b,
    const unsigned short* __restrict__ W2bfA, const unsigned short* __restrict__ W2bfB,
    const unsigned short* __restrict__ W2TbfA, const unsigned short* __restrict__ W2TbfB,
    const unsigned short* __restrict__ W1TbfA, const unsigned short* __restrict__ W1TbfB,
    const unsigned short* __restrict__ W1tailA, const unsigned short* __restrict__ W1tailB,
    const unsigned short* __restrict__ W3bfA, const unsigned short* __restrict__ W3bfB,
    float* __restrict__ out)
{
  __shared__ __align__(16) unsigned short buf0[64][264];  // h1a -> dh2c; sort alias
  __shared__ __align__(16) unsigned short buf1[64][264];  // h1b -> dh1_m
  __shared__ __align__(16) unsigned short xsm[64][32];    // bf16 x
  __shared__ __align__(16) float upool[1024];             // qpart[2][8][64] | redS[128][6]
  __shared__ float acur[64][6];
  __shared__ float Svv[64][6];
  __shared__ float XSsh[64];
  __shared__ float logps[64];
  __shared__ float asq[64];
  __shared__ int   selsh[64];
  __shared__ float medsh[2][2];

  float (*qpart)[8][64] = (float (*)[8][64])upool;
  float (*redS)[6] = (float (*)[6])upool;

  const int t = threadIdx.x;
  const int lane = t & 63, wv = t >> 6, quad = lane >> 4, l16 = lane & 15;
  const int b = blockIdx.x;
  const long abase = (long)b * 384;          // a0/out base (2 batches)
  const int wfrag = l16 * 32 + quad * 8;     // lane's short-offset within a 1KB tile
  const int bq = t >> 8;                     // batch half for sort/K phases
  const int tq = t & 255;                    // thread index within batch group
  const int eb = tq * 2;                     // this thread's 2 sort elements

  float* sortA = (float*)&buf0[0][0] + bq * 1024;  // 512 floats per batch
  float* sortB = sortA + 512;

  // triangular index map for sort elements 2tq, 2tq+1 (step-invariant, packed)
  int packij = 0;
  {
    #pragma unroll
    for (int m = 0; m < 2; ++m) {
      int e = eb + m;
      int ii = 0, jj = 0;
      if (e < 496) {
        float sq = sqrtf(992.25f - 2.0f * (float)e);
        ii = (int)(31.5f - sq);
        if (e >= ((ii + 1) * (62 - ii)) / 2) ++ii;
        else if (e < (ii * (63 - ii)) / 2) --ii;
        jj = ii + 1 + (e - (ii * (63 - ii)) / 2);
      }
      packij |= (ii | (jj << 5)) << (m * 10);
    }
  }

  // ---- init ----
  if (t < 384) { int r = t / 6, d = t - r * 6; acur[r][d] = a0[abase + t]; }
  if (t < 64) {
    float s = 0.f;
    #pragma unroll
    for (int d = 0; d < 6; ++d) { float x0 = a0[abase + t * 6 + d]; s += x0 * x0; }
    asq[t] = s; logps[t] = 0.f;
  }
  for (int idx = t; idx < 64 * 32; idx += 512) {
    int r = idx >> 5, k = idx & 31;
    float v = 0.f;
    if (k < 17) v = obs[((long)b * 64 + r) * 17 + k];
    else if (k < 23) v = a0[abase + r * 6 + (k - 17)];
    xsm[r][k] = f2bf(v);
  }
  __syncthreads();

  #pragma unroll 1
  for (int s = 0; s < 5; ++s) {
    // ---- sort element values (regs) from acur (per-batch triangle) ----
    float sv0 = 0.f, sv1 = 0.f;
    {
      int i0 = (packij & 31) + bq * 32, j0 = ((packij >> 5) & 31) + bq * 32;
      int i1 = ((packij >> 10) & 31) + bq * 32, j1 = ((packij >> 15) & 31) + bq * 32;
      #pragma unroll
      for (int d = 0; d < 6; ++d) {
        float d0 = acur[i0][d] - acur[j0][d]; sv0 += d0 * d0;
        float d1 = acur[i1][d] - acur[j1][d]; sv1 += d1 * d1;
      }
    }

    // ================= h1 both nets (swapped: A=W1T, B=x) ===================
    unsigned int m1a_bits = 0, m1b_bits = 0, m2a_bits = 0, m2b_bits = 0;
    {
      short8 bx[4];
      #pragma unroll
      for (int rt = 0; rt < 4; ++rt)
        bx[rt] = *(const short8*)&xsm[rt * 16 + l16][quad * 8];
      #pragma unroll 1
      for (int net = 0; net < 2; ++net) {
        const unsigned short* W1T = net ? W1TbfB : W1TbfA;
        const float* b1 = net ? b1b : b1a;
        unsigned short (*hbuf)[264] = net ? buf1 : buf0;
        unsigned int m1 = 0;
        #pragma unroll
        for (int c = 0; c < 2; ++c) {
          int ct = wv * 2 + c;
          short8 aw = *(const short8*)&W1T[ct * 512 + wfrag];
          f32x4 b1v = *(const f32x4*)&b1[ct * 16 + quad * 4];
          #pragma unroll
          for (int rt = 0; rt < 4; ++rt) {
            f32x4 z = {0.f, 0.f, 0.f, 0.f};
            f32x4 h = MFMA16(aw, bx[rt], z);
            float vg[4];
            #pragma unroll
            for (int g = 0; g < 4; ++g) {
              float v = h[g] + b1v[g];
              bool pos = (v > 0.f);
              if (pos) m1 |= 1u << ((rt * 2 + c) * 4 + g);
              vg[g] = pos ? v : 0.f;
            }
            uint2v pk;
            pk[0] = pkbf(vg[0], vg[1]);
            pk[1] = pkbf(vg[2], vg[3]);
            *(uint2v*)&hbuf[rt * 16 + l16][ct * 16 + quad * 4] = pk;
          }
        }
        if (net) m1b_bits = m1; else m1a_bits = m1;
      }
    }
    __syncthreads();  // B1

    // ================= h2 both nets + qpart (R7 structure) ==================
    #pragma unroll 1
    for (int net = 0; net < 2; ++net) {
      const unsigned short* W2T = net ? W2TbfB : W2TbfA;
      const float* b2 = net ? b2b : b2a;
      const float* W3 = net ? W3b : W3a;
      unsigned short (*hbuf)[264] = net ? buf1 : buf0;

      float pq[4] = {0.f, 0.f, 0.f, 0.f};
      unsigned int m2 = 0;

      #pragma unroll 1
      for (int ci = 0; ci < 2; ++ci) {
        int ct = wv * 2 + ci;
        f32x4 acc[4];
        acc[0] = acc[1] = acc[2] = acc[3] = (f32x4){0.f, 0.f, 0.f, 0.f};
        #pragma unroll 1
        for (int k = 0; k < 8; ++k) {
          short8 aw = *(const short8*)&W2T[ct * 4096 + k * 512 + wfrag];
          #pragma unroll
          for (int rt = 0; rt < 4; ++rt) {
            short8 hf = *(const short8*)&hbuf[rt * 16 + l16][k * 32 + quad * 8];
            acc[rt] = MFMA16(aw, hf, acc[rt]);
          }
        }
        f32x4 b2v = *(const f32x4*)&b2[ct * 16 + quad * 4];
        f32x4 w3v = *(const f32x4*)&W3[ct * 16 + quad * 4];
        #pragma unroll
        for (int rt = 0; rt < 4; ++rt)
          #pragma unroll
          for (int g = 0; g < 4; ++g) {
            float v = acc[rt][g] + b2v[g];
            if (v > 0.f) {
              m2 |= 1u << ((rt * 2 + ci) * 4 + g);
              pq[rt] += v * w3v[g];
            }
          }
      }
      if (net) m2b_bits = m2; else m2a_bits = m2;
      #pragma unroll
      for (int rt = 0; rt < 4; ++rt) {
        pq[rt] += __shfl_xor(pq[rt], 16);
        pq[rt] += __shfl_xor(pq[rt], 32);
      }
      if (quad == 0) {
        #pragma unroll
        for (int rt = 0; rt < 4; ++rt)
          qpart[net][wv][rt * 16 + l16] = pq[rt];
      }
    }
    __syncthreads();  // B2

    // ---- sel (t<64) + intra-wave sort k=2..128 (barrier bubble filler) ----
    if (t < 64) {
      float qa = b3a[0], qb = b3b[0];
      #pragma unroll
      for (int w = 0; w < 8; ++w) { qa += qpart[0][w][t]; qb += qpart[1][w][t]; }
      selsh[t] = (qa <= qb) ? 0 : 1;
    }
    #pragma unroll
    for (int k = 2; k <= 128; k <<= 1) {
      #pragma unroll
      for (int j = k >> 1; j >= 2; j >>= 1) {
        int lm = j >> 1;
        bool km = (((eb & j) == 0) == ((eb & k) == 0));
        float p0 = __shfl_xor(sv0, lm);
        sv0 = km ? fminf(sv0, p0) : fmaxf(sv0, p0);
        float p1 = __shfl_xor(sv1, lm);
        sv1 = km ? fminf(sv1, p1) : fmaxf(sv1, p1);
      }
      ce2(sv0, sv1, ((eb & k) == 0));
    }
    __syncthreads();  // B3

    // ---- dh2c: packed b64 masked writes -> buf0 (bf16 W3 from prep table) --
    #pragma unroll
    for (int ci = 0; ci < 2; ++ci) {
      int ct = wv * 2 + ci;
      short4v w3a4 = *(const short4v*)&W3bfA[ct * 16 + quad * 4];
      short4v w3b4 = *(const short4v*)&W3bfB[ct * 16 + quad * 4];
      #pragma unroll
      for (int rt = 0; rt < 4; ++rt) {
        int part = rt * 16 + l16;
        int sl = selsh[part];
        unsigned int mb = sl ? m2b_bits : m2a_bits;
        short4v dv;
        #pragma unroll
        for (int g = 0; g < 4; ++g) {
          int bit = (rt * 2 + ci) * 4 + g;
          short w3bf = sl ? w3b4[g] : w3a4[g];
          dv[g] = ((mb >> bit) & 1) ? w3bf : (short)0;
        }
        *(short4v*)&buf0[part][ct * 16 + quad * 4] = dv;
      }
    }
    __syncthreads();  // B4

    // ---- bwd: 4 passes (net x col), swapped; cvt_pk packed writes -> buf1 --
    #pragma unroll 1
    for (int pass = 0; pass < 4; ++pass) {
      int net = pass >> 1, c = pass & 1;
      int ct = wv * 2 + c;
      const unsigned short* W2f = net ? W2bfB : W2bfA;
      f32x4 acc[4];
      acc[0] = acc[1] = acc[2] = acc[3] = (f32x4){0.f, 0.f, 0.f, 0.f};
      #pragma unroll 1
      for (int k = 0; k < 8; ++k) {
        short8 aw = *(const short8*)&W2f[ct * 4096 + k * 512 + wfrag];
        #pragma unroll
        for (int rt = 0; rt < 4; ++rt) {
          short8 dd = *(const short8*)&buf0[rt * 16 + l16][k * 32 + quad * 8];
          acc[rt] = MFMA16(aw, dd, acc[rt]);
        }
      }
      unsigned int mb = net ? m1b_bits : m1a_bits;
      #pragma unroll
      for (int rt = 0; rt < 4; ++rt) {
        int part = rt * 16 + l16;
        if (selsh[part] == net) {
          float vm[4];
          #pragma unroll
          for (int g = 0; g < 4; ++g) {
            int bit = (rt * 2 + c) * 4 + g;
            vm[g] = ((mb >> bit) & 1) ? acc[rt][g] : 0.f;
          }
          uint2v pk;
          pk[0] = pkbf(vm[0], vm[1]);
          pk[1] = pkbf(vm[2], vm[3]);
          *(uint2v*)&buf1[part][ct * 16 + quad * 4] = pk;
        }
      }
    }
    __syncthreads();  // B5

    // ---- S (wave: net = wv>>2, rt = wv&3; swapped) + sort stage1 write ----
    {
      int netS = wv >> 2, rt = wv & 3;
      const unsigned short* Wt = netS ? W1tailB : W1tailA;
      f32x4 sacc = {0.f, 0.f, 0.f, 0.f};
      #pragma unroll 1
      for (int k = 0; k < 8; ++k) {
        short8 a = *(const short8*)&buf1[rt * 16 + l16][k * 32 + quad * 8];
        short8 bb2 = *(const short8*)&Wt[k * 512 + wfrag];
        sacc = MFMA16(bb2, a, sacc);   // lane: 4 d-rows x 1 particle
      }
      #pragma unroll
      for (int g = 0; g < 4; ++g) {
        int d = quad * 4 + g;
        if (d < 6) redS[netS * 64 + rt * 16 + l16][d] = sacc[g];
      }
    }
    sortA[eb] = sv0; sortA[eb + 1] = sv1;
    __syncthreads();  // B6

    // ---- sort stage1 read (k=256, j=128) + tail + Svv fill + stage2 write --
    {
      bool km = (((eb & 128) == 0) == ((eb & 256) == 0));
      float p0 = sortA[eb ^ 128];
      float p1 = sortA[(eb ^ 128) + 1];
      sv0 = km ? fminf(sv0, p0) : fmaxf(sv0, p0);
      sv1 = km ? fminf(sv1, p1) : fmaxf(sv1, p1);
      #pragma unroll
      for (int j = 64; j >= 2; j >>= 1) {
        int lm = j >> 1;
        bool k2 = (((eb & j) == 0) == ((eb & 256) == 0));
        float q0 = __shfl_xor(sv0, lm);
        sv0 = k2 ? fminf(sv0, q0) : fmaxf(sv0, q0);
        float q1 = __shfl_xor(sv1, lm);
        sv1 = k2 ? fminf(sv1, q1) : fmaxf(sv1, q1);
      }
      ce2(sv0, sv1, ((eb & 256) == 0));
    }
    if (t < 384) { int r = t / 6, d = t - r * 6; Svv[r][d] = redS[selsh[r] * 64 + r][d]; }
    sortB[eb] = sv0; sortB[eb + 1] = sv1;
    __syncthreads();  // B7

    // ---- sort stage2 read (k=512, j=256) + XSsh + stage3 write ----
    {
      bool km = ((eb & 256) == 0);
      float p0 = sortB[eb ^ 256];
      float p1 = sortB[(eb ^ 256) + 1];
      sv0 = km ? fminf(sv0, p0) : fmaxf(sv0, p0);
      sv1 = km ? fminf(sv1, p1) : fmaxf(sv1, p1);
    }
    if (t < 64) {
      float sx = 0.f;
      #pragma unroll
      for (int d = 0; d < 6; ++d) sx += acur[t][d] * Svv[t][d];
      XSsh[t] = sx;
    }
    sortA[eb] = sv0; sortA[eb + 1] = sv1;
    __syncthreads();  // B8

    // ---- sort stage3 read (j=128) + final tail + median ----
    {
      bool km = ((eb & 128) == 0);
      float p0 = sortA[eb ^ 128];
      float p1 = sortA[(eb ^ 128) + 1];
      sv0 = km ? fminf(sv0, p0) : fmaxf(sv0, p0);
      sv1 = km ? fminf(sv1, p1) : fmaxf(sv1, p1);
      #pragma unroll
      for (int j = 64; j >= 2; j >>= 1) {
        int lm = j >> 1;
        bool k2 = ((eb & j) == 0);
        float q0 = __shfl_xor(sv0, lm);
        sv0 = k2 ? fminf(sv0, q0) : fmaxf(sv0, q0);
        float q1 = __shfl_xor(sv1, lm);
        sv1 = k2 ? fminf(sv1, q1) : fmaxf(sv1, q1);
      }
      ce2(sv0, sv1, true);
    }
    if (tq == 127) medsh[bq][0] = sv1;  // element 255 of this batch
    if (tq == 128) medsh[bq][1] = sv0;  // element 256 of this batch
    __syncthreads();  // B9

    // ================= K row-sums + update (R7 form) ========================
    float med = 0.5f * (medsh[bq][0] + medsh[bq][1]);
    float g = 1.0f / (2.0f * (med / logf(33.0f)) + 1e-8f);

    const int i = t >> 3, l = t & 7;   // i in [0,64); batch of row i = bq
    const int jb = i & 32;             // batch row base
    float ai0 = acur[i][0], ai1 = acur[i][1], ai2 = acur[i][2];
    float ai3 = acur[i][3], ai4 = acur[i][4], ai5 = acur[i][5];
    float ks0=0,ks1=0,ks2=0,ks3=0,ks4=0,ks5=0;
    float kx0=0,kx1=0,kx2=0,kx3=0,kx4=0,kx5=0;
    float krow=0.f, kd2=0.f, kxs=0.f;
    #pragma unroll
    for (int jj = 0; jj < 4; ++jj) {
      int j = jb + l + 8 * jj;
      float aj0 = acur[j][0], aj1 = acur[j][1], aj2 = acur[j][2];
      float aj3 = acur[j][3], aj4 = acur[j][4], aj5 = acur[j][5];
      float dv = 0.f, df;
      df = ai0 - aj0; dv += df * df;
      df = ai1 - aj1; dv += df * df;
      df = ai2 - aj2; dv += df * df;
      df = ai3 - aj3; dv += df * df;
      df = ai4 - aj4; dv += df * df;
      df = ai5 - aj5; dv += df * df;
      float kv = expf(-g * dv);
      krow += kv; kd2 += kv * dv; kxs += kv * XSsh[j];
      ks0 += kv * Svv[j][0]; kx0 += kv * aj0;
      ks1 += kv * Svv[j][1]; kx1 += kv * aj1;
      ks2 += kv * Svv[j][2]; kx2 += kv * aj2;
      ks3 += kv * Svv[j][3]; kx3 += kv * aj3;
      ks4 += kv * Svv[j][4]; kx4 += kv * aj4;
      ks5 += kv * Svv[j][5]; kx5 += kv * aj5;
    }
    #pragma unroll
    for (int off = 4; off > 0; off >>= 1) {
      krow += __shfl_down(krow, off, 8);
      kd2  += __shfl_down(kd2,  off, 8);
      kxs  += __shfl_down(kxs,  off, 8);
      ks0 += __shfl_down(ks0, off, 8); kx0 += __shfl_down(kx0, off, 8);
      ks1 += __shfl_down(ks1, off, 8); kx1 += __shfl_down(kx1, off, 8);
      ks2 += __shfl_down(ks2, off, 8); kx2 += __shfl_down(kx2, off, 8);
      ks3 += __shfl_down(ks3, off, 8); kx3 += __shfl_down(kx3, off, 8);
      ks4 += __shfl_down(ks4, off, 8); kx4 += __shfl_down(kx4, off, 8);
      ks5 += __shfl_down(ks5, off, 8); kx5 += __shfl_down(kx5, off, 8);
    }
    float an0=0,an1=0,an2=0,an3=0,an4=0,an5=0, lpnew=0;
    if (l == 0) {
      const float inv_n = 1.0f / 32.0f;
      float t1sum = 0.f, p;
      p = (ks0 + 2.f*g*(ai0*krow - kx0)) * inv_n; an0 = ai0 + LR * p; t1sum += ai0 * ks0;
      p = (ks1 + 2.f*g*(ai1*krow - kx1)) * inv_n; an1 = ai1 + LR * p; t1sum += ai1 * ks1;
      p = (ks2 + 2.f*g*(ai2*krow - kx2)) * inv_n; an2 = ai2 + LR * p; t1sum += ai2 * ks2;
      p = (ks3 + 2.f*g*(ai3*krow - kx3)) * inv_n; an3 = ai3 + LR * p; t1sum += ai3 * ks3;
      p = (ks4 + 2.f*g*(ai4*krow - kx4)) * inv_n; an4 = ai4 + LR * p; t1sum += ai4 * ks4;
      p = (ks5 + 2.f*g*(ai5*krow - kx5)) * inv_n; an5 = ai5 + LR * p; t1sum += ai5 * ks5;
      float term1 = (-2.f * g / 31.f) * (t1sum - kxs);
      float term2 = (-2.f * g / 31.f) * (2.f * g * kd2 - 6.f * (krow - 1.f));
      lpnew = logps[i] - LR * (term1 + term2);
    }
    __syncthreads();  // B10
    if (l == 0) {
      acur[i][0] = an0; acur[i][1] = an1; acur[i][2] = an2;
      acur[i][3] = an3; acur[i][4] = an4; acur[i][5] = an5;
      logps[i] = lpnew;
      xsm[i][17] = f2bf(an0); xsm[i][18] = f2bf(an1); xsm[i][19] = f2bf(an2);
      xsm[i][20] = f2bf(an3); xsm[i][21] = f2bf(an4); xsm[i][22] = f2bf(an5);
    }
    __syncthreads();  // B11
  }

  // ================= epilogue =================
  if (t < 384) { int r = t / 6, d = t - r * 6; out[abase + t] = tanhf(acur[r][d]); }
  if (t < 64) {
    float st = 0.f;
    #pragma unroll
    for (int d = 0; d < 6; ++d) {
      float x = acur[t][d];
      float z = -2.f * x;
      float sp = fmaxf(z, 0.f) + log1pf(expf(-fabsf(z)));
      st += 2.f * (0.69314718056f - x - sp);
    }
    float lpn = -3.0f * logf(1.88495559215f) - (0.5f / 0.3f) * asq[t];
    XSsh[t] = lpn + logps[t] - st;
  }
  __syncthreads();
  if (tq == 0) {
    float s = 0.f;
    #pragma unroll
    for (int n = 0; n < 32; ++n) s += XSsh[bq * 32 + n];
    out[196608 + 2 * b + bq] = s * (1.0f / 32.0f);
  }
}

extern "C" void kernel_launch(void* const* d_in, const int* in_sizes, int n_in,
                              void* d_out, int out_size, void* d_ws, size_t ws_size,
                              hipStream_t stream) {
  const float* obs  = (const float*)d_in[0];
  const float* a0   = (const float*)d_in[1];
  const float* q1W1 = (const float*)d_in[2];
  const float* q1b1 = (const float*)d_in[3];
  const float* q1W2 = (const float*)d_in[4];
  const float* q1b2 = (const float*)d_in[5];
  const float* q1W3 = (const float*)d_in[6];
  const float* q1b3 = (const float*)d_in[7];
  const float* q2W1 = (const float*)d_in[8];
  const float* q2b1 = (const float*)d_in[9];
  const float* q2W2 = (const float*)d_in[10];
  const float* q2b2 = (const float*)d_in[11];
  const float* q2W3 = (const float*)d_in[12];
  const float* q2b3 = (const float*)d_in[13];

  unsigned short* wsu = (unsigned short*)d_ws;
  unsigned short* W2bfA  = wsu;
  unsigned short* W2bfB  = W2bfA + 65536;
  unsigned short* W2TbfA = W2bfB + 65536;
  unsigned short* W2TbfB = W2TbfA + 65536;
  unsigned short* W1TbfA = W2TbfB + 65536;
  unsigned short* W1TbfB = W1TbfA + 8192;
  unsigned short* W1tailA = W1TbfB + 8192;
  unsigned short* W1tailB = W1tailA + 4096;
  unsigned short* W3bfA   = W1tailB + 4096;
  unsigned short* W3bfB   = W3bfA + 256;
  float* out  = (float*)d_out;

  prep_kernel<<<1122, 256, 0, stream>>>(q1W1, q2W1, q1W2, q2W2, q1W3, q2W3,
      W2bfA, W2bfB, W2TbfA, W2TbfB, W1TbfA, W1TbfB, W1tailA, W1tailB,
      W3bfA, W3bfB);

  fused_kernel<<<512, 512, 0, stream>>>(obs, a0,
      q1b1, q1b2, q1W3, q1b3,
      q2b1, q2b2, q2W3, q2b3,
      W2bfA, W2bfB, W2TbfA, W2TbfB, W1TbfA, W1TbfB, W1tailA, W1tailB,
      W3bfA, W3bfB,
      out);
}